// Round 4
// baseline (72.041 us; speedup 1.0000x reference)
//
#include <hip/hip_runtime.h>
#include <math.h>

#define B_TOT 1024
#define IN_N  128
#define IN_D  16
#define NCAP  32
#define DCAP  32

typedef __attribute__((ext_vector_type(8)))  short bf16x8;
typedef __attribute__((ext_vector_type(16))) float f32x16;
typedef unsigned int  uint_;
typedef unsigned short ushort_;

__device__ __forceinline__ uint_ cvt_pk_bf16(float lo, float hi) {
    uint_ r;
    asm("v_cvt_pk_bf16_f32 %0, %1, %2" : "=v"(r) : "v"(lo), "v"(hi));
    return r;
}
__device__ __forceinline__ float bf16_to_f(ushort_ h) {
    return __uint_as_float(((uint_)h) << 16);
}

// ---------------------------------------------------------------------------
// prep (fused): blocks [0,512): W[n][j][i][z] -> WT[((n*128+j)*32+z)*16+i] bf16
//               blocks [512,1024): x transpose tiles -> XW[(j*2+ib)*1024+b][8]
// ---------------------------------------------------------------------------
__global__ __launch_bounds__(256)
void prep(const float* __restrict__ x, const float* __restrict__ W,
          ushort_* __restrict__ XW, ushort_* __restrict__ WT) {
    const int blk = blockIdx.x;
    const int t   = threadIdx.x;

    if (blk < 512) {
        const int q  = blk * 256 + t;       // 131072 = 32n*128j*32z
        const int z  = q & 31;
        const int nj = q >> 5;
        const float* p = W + (size_t)nj * (IN_D * DCAP) + z;
        float f[16];
#pragma unroll
        for (int i = 0; i < 16; ++i) f[i] = p[i * 32];
        uint4 lo, hi;
        lo.x = cvt_pk_bf16(f[0],  f[1]);  lo.y = cvt_pk_bf16(f[2],  f[3]);
        lo.z = cvt_pk_bf16(f[4],  f[5]);  lo.w = cvt_pk_bf16(f[6],  f[7]);
        hi.x = cvt_pk_bf16(f[8],  f[9]);  hi.y = cvt_pk_bf16(f[10], f[11]);
        hi.z = cvt_pk_bf16(f[12], f[13]); hi.w = cvt_pk_bf16(f[14], f[15]);
        uint4* dst = (uint4*)(WT + (size_t)q * 16);
        dst[0] = lo; dst[1] = hi;
        return;
    }

    // prep_x: LDS transpose, tile = 64 b x 64 cols (c = j*16+i)
    const int id = blk - 512;
    const int tb = id >> 5;
    const int tc = id & 31;
    const int b0 = tb * 64, c0 = tc * 64;

    __shared__ ushort_ lds[64][72];

    {
        const int c4 = t & 15;
#pragma unroll
        for (int k = 0; k < 4; ++k) {
            const int r = (t >> 4) + 16 * k;
            const float4 f = *(const float4*)(x + (size_t)(b0 + r) * 2048 + c0 + c4 * 4);
            uint2 o;
            o.x = cvt_pk_bf16(f.x, f.y);
            o.y = cvt_pk_bf16(f.z, f.w);
            *(uint2*)&lds[r][c4 * 4] = o;
        }
    }
    __syncthreads();

    const int jb2l = t >> 5;
    const int jb20 = tc * 8;
#pragma unroll
    for (int h = 0; h < 2; ++h) {
        const int bl = (t & 31) + h * 32;
        bf16x8 v = *(const bf16x8*)&lds[bl][jb2l * 8];
        *(bf16x8*)(XW + ((size_t)(jb20 + jb2l) * 1024 + b0 + bl) * 8) = v;
    }
}

// ---------------------------------------------------------------------------
// kA: block = (n, 64-b tile); 4 waves x 32 j. A-frag (WT) shared by the two
// b-column MFMAs. Phase 1: usum via 4 independent chains; LDS combine.
// Phase 2: recompute u per j, dot with usum -> logits bf16 (all 64 lanes
// store: hi-half lanes store the b+32 column).
// ---------------------------------------------------------------------------
__global__ __launch_bounds__(256, 4)
void kA(const ushort_* __restrict__ XW, const ushort_* __restrict__ WT,
        ushort_* __restrict__ LC) {
    const int raw = blockIdx.x;                      // 512 = 32n * 8 btiles... (swz)
    const int bid = ((raw & 7) << 6) | (raw >> 3);   // bijective XCD swizzle
    const int n   = bid >> 4;
    const int cb0 = (bid & 15) * 64;
    const int t   = threadIdx.x;
    const int wv  = t >> 6;
    const int l   = t & 63;
    const int lo5 = l & 31;
    const int hi  = l >> 5;

    __shared__ float xch[4][2][16 * 64];             // 32 KB

    const ushort_* aBase = WT + ((size_t)(n * IN_N) * 32 + lo5) * 16 + (size_t)hi * 8;
    const ushort_* bBase = XW + ((size_t)hi * 1024 + cb0 + lo5) * 8;  // +256 for b+32

    const int jbeg = wv * 32;

    f32x16 ul0, uh0, ul1, uh1;
#pragma unroll
    for (int r = 0; r < 16; ++r) { ul0[r] = 0.f; uh0[r] = 0.f; ul1[r] = 0.f; uh1[r] = 0.f; }

    for (int j = jbeg; j < jbeg + 32; j += 2) {
        bf16x8 a0  = *(const bf16x8*)(aBase + (size_t)j * 512);
        bf16x8 xl0 = *(const bf16x8*)(bBase + (size_t)j * 16384);
        bf16x8 xh0 = *(const bf16x8*)(bBase + (size_t)j * 16384 + 256);
        bf16x8 a1  = *(const bf16x8*)(aBase + (size_t)(j + 1) * 512);
        bf16x8 xl1 = *(const bf16x8*)(bBase + (size_t)(j + 1) * 16384);
        bf16x8 xh1 = *(const bf16x8*)(bBase + (size_t)(j + 1) * 16384 + 256);
        ul0 = __builtin_amdgcn_mfma_f32_32x32x16_bf16(a0, xl0, ul0, 0, 0, 0);
        uh0 = __builtin_amdgcn_mfma_f32_32x32x16_bf16(a0, xh0, uh0, 0, 0, 0);
        ul1 = __builtin_amdgcn_mfma_f32_32x32x16_bf16(a1, xl1, ul1, 0, 0, 0);
        uh1 = __builtin_amdgcn_mfma_f32_32x32x16_bf16(a1, xh1, uh1, 0, 0, 0);
    }
#pragma unroll
    for (int r = 0; r < 16; ++r) { ul0[r] += ul1[r]; uh0[r] += uh1[r]; }

    // per-lane-contiguous exchange: 4x ds_write_b128, 2-way alias (free)
    {
        float4* dl = (float4*)&xch[wv][0][l * 16];
        float4* dh = (float4*)&xch[wv][1][l * 16];
#pragma unroll
        for (int g = 0; g < 4; ++g) {
            dl[g] = (float4){ul0[g*4], ul0[g*4+1], ul0[g*4+2], ul0[g*4+3]};
            dh[g] = (float4){uh0[g*4], uh0[g*4+1], uh0[g*4+2], uh0[g*4+3]};
        }
    }
    __syncthreads();

    f32x16 usl, ush;
#pragma unroll
    for (int g = 0; g < 4; ++g) {
        float4 sl = (float4){0.f, 0.f, 0.f, 0.f}, sh = sl;
#pragma unroll
        for (int w = 0; w < 4; ++w) {
            const float4 al = *(const float4*)&xch[w][0][l * 16 + g * 4];
            const float4 ah = *(const float4*)&xch[w][1][l * 16 + g * 4];
            sl.x += al.x; sl.y += al.y; sl.z += al.z; sl.w += al.w;
            sh.x += ah.x; sh.y += ah.y; sh.z += ah.z; sh.w += ah.w;
        }
        usl[g*4] = sl.x; usl[g*4+1] = sl.y; usl[g*4+2] = sl.z; usl[g*4+3] = sl.w;
        ush[g*4] = sh.x; ush[g*4+1] = sh.y; ush[g*4+2] = sh.z; ush[g*4+3] = sh.w;
    }

    const float rsqD = 0.17677669529663689f;  // 1/sqrt(32)
    f32x16 zc;
#pragma unroll
    for (int r = 0; r < 16; ++r) zc[r] = 0.f;

#pragma unroll 2
    for (int j = jbeg; j < jbeg + 32; ++j) {
        bf16x8 af = *(const bf16x8*)(aBase + (size_t)j * 512);
        bf16x8 xl = *(const bf16x8*)(bBase + (size_t)j * 16384);
        bf16x8 xh = *(const bf16x8*)(bBase + (size_t)j * 16384 + 256);
        f32x16 ulo = __builtin_amdgcn_mfma_f32_32x32x16_bf16(af, xl, zc, 0, 0, 0);
        f32x16 uhi = __builtin_amdgcn_mfma_f32_32x32x16_bf16(af, xh, zc, 0, 0, 0);
        float pl0 = ulo[0] * usl[0], pl1 = ulo[1] * usl[1];
        float ph0 = uhi[0] * ush[0], ph1 = uhi[1] * ush[1];
#pragma unroll
        for (int r = 2; r < 16; r += 2) {
            pl0 = fmaf(ulo[r],     usl[r],     pl0);
            pl1 = fmaf(ulo[r + 1], usl[r + 1], pl1);
            ph0 = fmaf(uhi[r],     ush[r],     ph0);
            ph1 = fmaf(uhi[r + 1], ush[r + 1], ph1);
        }
        float pl = pl0 + pl1;
        float ph = ph0 + ph1;
        pl += __shfl_xor(pl, 32);
        ph += __shfl_xor(ph, 32);
        const float p = (hi ? ph : pl) * rsqD;
        uint_ pk = cvt_pk_bf16(p, p);
        LC[(size_t)(n * IN_N + j) * 1024 + cb0 + hi * 32 + lo5] = (ushort_)(pk & 0xffffu);
    }
}

// ---------------------------------------------------------------------------
// kB: softmax over n per (b,j), 2 b's per thread (packed uint), + bias.
// ---------------------------------------------------------------------------
__global__ __launch_bounds__(256)
void kB(const float* __restrict__ bias, ushort_* __restrict__ LC) {
    const int t  = blockIdx.x * 256 + threadIdx.x;  // 65536 = 128j * 512 bpair
    const int j  = t >> 9;                           // uniform per block
    const int bp = (t & 511) * 2;
    float vl[NCAP], vh[NCAP];
    float ml = -1e30f, mh = -1e30f;
#pragma unroll
    for (int n = 0; n < NCAP; ++n) {
        const uint_ w = *(const uint_*)(LC + (size_t)(n * IN_N + j) * 1024 + bp);
        vl[n] = bf16_to_f((ushort_)(w & 0xffffu));
        vh[n] = bf16_to_f((ushort_)(w >> 16));
        ml = fmaxf(ml, vl[n]);
        mh = fmaxf(mh, vh[n]);
    }
    float sl = 0.f, sh = 0.f;
#pragma unroll
    for (int n = 0; n < NCAP; ++n) {
        vl[n] = __expf(vl[n] - ml); sl += vl[n];
        vh[n] = __expf(vh[n] - mh); sh += vh[n];
    }
    const float il = 1.f / sl, ih = 1.f / sh;
#pragma unroll
    for (int n = 0; n < NCAP; ++n) {
        const float bb = bias[n * IN_N + j];
        const float cl = vl[n] * il + bb;
        const float ch = vh[n] * ih + bb;
        *(uint_*)(LC + (size_t)(n * IN_N + j) * 1024 + bp) = cvt_pk_bf16(cl, ch);
    }
}

// ---------------------------------------------------------------------------
// kC: s[b,n,z] = sum_j c * u; btile=64, 4 waves x 32 j; wave-0 epilogue.
// ---------------------------------------------------------------------------
__global__ __launch_bounds__(256, 4)
void kC(const ushort_* __restrict__ XW, const ushort_* __restrict__ WT,
        const ushort_* __restrict__ LC, float* __restrict__ out) {
    const int raw = blockIdx.x;
    const int bid = ((raw & 7) << 6) | (raw >> 3);
    const int n   = bid >> 4;
    const int cb0 = (bid & 15) * 64;
    const int t   = threadIdx.x;
    const int wv  = t >> 6;
    const int l   = t & 63;
    const int lo5 = l & 31;
    const int hi  = l >> 5;

    __shared__ float xch[3][2][16 * 64];             // 24 KB

    const ushort_* aBase = WT + ((size_t)(n * IN_N) * 32 + lo5) * 16 + (size_t)hi * 8;
    const ushort_* bBase = XW + ((size_t)hi * 1024 + cb0 + lo5) * 8;
    const ushort_* cBase = LC + (size_t)(n * IN_N) * 1024 + cb0 + lo5;

    f32x16 sl, sh, zc;
#pragma unroll
    for (int r = 0; r < 16; ++r) { sl[r] = 0.f; sh[r] = 0.f; zc[r] = 0.f; }

    const int jbeg = wv * 32;
#pragma unroll 2
    for (int j = jbeg; j < jbeg + 32; ++j) {
        bf16x8 af = *(const bf16x8*)(aBase + (size_t)j * 512);
        bf16x8 xl = *(const bf16x8*)(bBase + (size_t)j * 16384);
        bf16x8 xh = *(const bf16x8*)(bBase + (size_t)j * 16384 + 256);
        const float cl = bf16_to_f(cBase[(size_t)j * 1024]);
        const float ch = bf16_to_f(cBase[(size_t)j * 1024 + 32]);
        f32x16 ulo = __builtin_amdgcn_mfma_f32_32x32x16_bf16(af, xl, zc, 0, 0, 0);
        f32x16 uhi = __builtin_amdgcn_mfma_f32_32x32x16_bf16(af, xh, zc, 0, 0, 0);
#pragma unroll
        for (int r = 0; r < 16; ++r) {
            sl[r] = fmaf(cl, ulo[r], sl[r]);
            sh[r] = fmaf(ch, uhi[r], sh[r]);
        }
    }

    if (wv > 0) {
        float4* dl = (float4*)&xch[wv - 1][0][l * 16];
        float4* dh = (float4*)&xch[wv - 1][1][l * 16];
#pragma unroll
        for (int g = 0; g < 4; ++g) {
            dl[g] = (float4){sl[g*4], sl[g*4+1], sl[g*4+2], sl[g*4+3]};
            dh[g] = (float4){sh[g*4], sh[g*4+1], sh[g*4+2], sh[g*4+3]};
        }
    }
    __syncthreads();

    if (wv == 0) {
#pragma unroll
        for (int g = 0; g < 4; ++g) {
#pragma unroll
            for (int w = 0; w < 3; ++w) {
                const float4 al = *(const float4*)&xch[w][0][l * 16 + g * 4];
                const float4 ah = *(const float4*)&xch[w][1][l * 16 + g * 4];
                sl[g*4]   += al.x; sl[g*4+1] += al.y; sl[g*4+2] += al.z; sl[g*4+3] += al.w;
                sh[g*4]   += ah.x; sh[g*4+1] += ah.y; sh[g*4+2] += ah.z; sh[g*4+3] += ah.w;
            }
        }
        float ql = 0.f, qh = 0.f;
#pragma unroll
        for (int r = 0; r < 16; ++r) {
            ql = fmaf(sl[r], sl[r], ql);
            qh = fmaf(sh[r], sh[r], qh);
        }
        ql += __shfl_xor(ql, 32);
        qh += __shfl_xor(qh, 32);
        const float nl = sqrtf(ql);
        const float nh = sqrtf(qh);
        const float fl = (1.f - 1.f / (__expf(nl) + 1e-20f)) / (nl + 1e-20f);
        const float fh = (1.f - 1.f / (__expf(nh) + 1e-20f)) / (nh + 1e-20f);
        // lane (lo5,hi), reg r -> z = (r&3) + 8*(r>>2) + 4*hi
        float* opl = out + ((size_t)(cb0 + lo5) * NCAP + n) * DCAP + hi * 4;
        float* oph = opl + (size_t)32 * NCAP * DCAP;
#pragma unroll
        for (int g = 0; g < 4; ++g) {
            float4 v4 = { sl[g*4] * fl, sl[g*4+1] * fl, sl[g*4+2] * fl, sl[g*4+3] * fl };
            *(float4*)(opl + g * 8) = v4;
            float4 w4 = { sh[g*4] * fh, sh[g*4+1] * fh, sh[g*4+2] * fh, sh[g*4+3] * fh };
            *(float4*)(oph + g * 8) = w4;
        }
    }
}

// ---------------------------------------------------------------------------
extern "C" void kernel_launch(void* const* d_in, const int* in_sizes, int n_in,
                              void* d_out, int out_size, void* d_ws, size_t ws_size,
                              hipStream_t stream) {
    const float* x    = (const float*)d_in[0];   // [1024,128,16]
    const float* W    = (const float*)d_in[1];   // [32,128,16,32]
    const float* bias = (const float*)d_in[2];   // [32,128,1]
    float* out = (float*)d_out;                  // [1024,32,32]

    char* ws = (char*)d_ws;
    ushort_* XW = (ushort_*)ws;                  // 4 MB bf16 x, relaid
    ushort_* WT = (ushort_*)(ws + (4u << 20));   // 4 MB bf16 W^T
    ushort_* LC = (ushort_*)(ws + (8u << 20));   // 8 MB bf16 logits/c

    prep<<<1024, 256, 0, stream>>>(x, W, XW, WT);
    kA<<<512, 256, 0, stream>>>(XW, WT, LC);
    kB<<<256, 256, 0, stream>>>(bias, LC);
    kC<<<512, 256, 0, stream>>>(XW, WT, LC, out);
}

// Round 5
// 65.124 us; speedup vs baseline: 1.1062x; 1.1062x over previous
//
#include <hip/hip_runtime.h>
#include <math.h>

#define B_TOT 1024
#define IN_N  128
#define IN_D  16
#define NCAP  32
#define DCAP  32

typedef __attribute__((ext_vector_type(8)))  short bf16x8;
typedef __attribute__((ext_vector_type(16))) float f32x16;
typedef unsigned int  uint_;
typedef unsigned short ushort_;

__device__ __forceinline__ uint_ cvt_pk_bf16(float lo, float hi) {
    uint_ r;
    asm("v_cvt_pk_bf16_f32 %0, %1, %2" : "=v"(r) : "v"(lo), "v"(hi));
    return r;
}
__device__ __forceinline__ float bf16_to_f(ushort_ h) {
    return __uint_as_float(((uint_)h) << 16);
}

// ---------------------------------------------------------------------------
// prep (fused): blocks [0,512): W[n][j][i][z] -> WT[((n*128+j)*32+z)*16+i] bf16
//               blocks [512,1024): x transpose -> XW[(j*2+ib)*1024+b][8] bf16
// ---------------------------------------------------------------------------
__global__ __launch_bounds__(256)
void prep(const float* __restrict__ x, const float* __restrict__ W,
          ushort_* __restrict__ XW, ushort_* __restrict__ WT) {
    const int blk = blockIdx.x;
    const int t   = threadIdx.x;

    if (blk < 512) {
        const int q  = blk * 256 + t;       // 131072 = 32n*128j*32z
        const int z  = q & 31;
        const int nj = q >> 5;
        const float* p = W + (size_t)nj * (IN_D * DCAP) + z;
        float f[16];
#pragma unroll
        for (int i = 0; i < 16; ++i) f[i] = p[i * 32];
        uint4 lo, hi;
        lo.x = cvt_pk_bf16(f[0],  f[1]);  lo.y = cvt_pk_bf16(f[2],  f[3]);
        lo.z = cvt_pk_bf16(f[4],  f[5]);  lo.w = cvt_pk_bf16(f[6],  f[7]);
        hi.x = cvt_pk_bf16(f[8],  f[9]);  hi.y = cvt_pk_bf16(f[10], f[11]);
        hi.z = cvt_pk_bf16(f[12], f[13]); hi.w = cvt_pk_bf16(f[14], f[15]);
        uint4* dst = (uint4*)(WT + (size_t)q * 16);
        dst[0] = lo; dst[1] = hi;
        return;
    }

    // prep_x: LDS transpose, tile = 64 b x 64 cols (c = j*16+i)
    const int id = blk - 512;
    const int tb = id >> 5;
    const int tc = id & 31;
    const int b0 = tb * 64, c0 = tc * 64;

    __shared__ ushort_ lds[64][72];

    {
        const int c4 = t & 15;
#pragma unroll
        for (int k = 0; k < 4; ++k) {
            const int r = (t >> 4) + 16 * k;
            const float4 f = *(const float4*)(x + (size_t)(b0 + r) * 2048 + c0 + c4 * 4);
            uint2 o;
            o.x = cvt_pk_bf16(f.x, f.y);
            o.y = cvt_pk_bf16(f.z, f.w);
            *(uint2*)&lds[r][c4 * 4] = o;
        }
    }
    __syncthreads();

    const int jb2l = t >> 5;
    const int jb20 = tc * 8;
#pragma unroll
    for (int h = 0; h < 2; ++h) {
        const int bl = (t & 31) + h * 32;
        bf16x8 v = *(const bf16x8*)&lds[bl][jb2l * 8];
        *(bf16x8*)(XW + ((size_t)(jb20 + jb2l) * 1024 + b0 + bl) * 8) = v;
    }
}

// ---------------------------------------------------------------------------
// kA: 512 blocks x 512 threads. Block = (n, 64-b tile); wave (jw,bh):
// jw = 32-j chunk, bh = 32-b half (A-frags shared across bh via L1).
// Phase 1: usum, 2 MFMA chains/wave; LDS combine over jw.
// Phase 2: recompute u per j-pair, dot with usum -> logits; lo-half lanes
// store j, hi-half store j+1 (all 64 lanes store).
// ---------------------------------------------------------------------------
__global__ __launch_bounds__(512, 2)
void kA(const ushort_* __restrict__ XW, const ushort_* __restrict__ WT,
        ushort_* __restrict__ LC) {
    const int raw = blockIdx.x;                      // 512
    const int bid = ((raw & 7) << 6) | (raw >> 3);   // bijective XCD swizzle
    const int n   = bid >> 4;
    const int cb0 = (bid & 15) * 64;
    const int t   = threadIdx.x;
    const int w   = t >> 6;                          // 0..7
    const int jw  = w >> 1;                          // 0..3
    const int bh  = w & 1;                           // 0..1
    const int l   = t & 63;
    const int lo5 = l & 31;
    const int hi  = l >> 5;

    __shared__ float xch[4][2][16 * 64];             // 32 KB [jw][bh]

    const ushort_* aBase = WT + ((size_t)(n * IN_N) * 32 + lo5) * 16 + (size_t)hi * 8;
    const ushort_* bBase = XW + ((size_t)hi * 1024 + cb0 + bh * 32 + lo5) * 8;

    const int jbeg = jw * 32;

    f32x16 us0, us1;
#pragma unroll
    for (int r = 0; r < 16; ++r) { us0[r] = 0.f; us1[r] = 0.f; }

    for (int j = jbeg; j < jbeg + 32; j += 2) {
        bf16x8 a0 = *(const bf16x8*)(aBase + (size_t)j * 512);
        bf16x8 x0 = *(const bf16x8*)(bBase + (size_t)j * 16384);
        bf16x8 a1 = *(const bf16x8*)(aBase + (size_t)(j + 1) * 512);
        bf16x8 x1 = *(const bf16x8*)(bBase + (size_t)(j + 1) * 16384);
        us0 = __builtin_amdgcn_mfma_f32_32x32x16_bf16(a0, x0, us0, 0, 0, 0);
        us1 = __builtin_amdgcn_mfma_f32_32x32x16_bf16(a1, x1, us1, 0, 0, 0);
    }
#pragma unroll
    for (int r = 0; r < 16; ++r) us0[r] += us1[r];

    // per-lane-contiguous exchange (4x ds_write_b128; 2-way alias = free)
    {
        float4* d = (float4*)&xch[jw][bh][l * 16];
#pragma unroll
        for (int g = 0; g < 4; ++g)
            d[g] = (float4){us0[g*4], us0[g*4+1], us0[g*4+2], us0[g*4+3]};
    }
    __syncthreads();

    f32x16 us;
#pragma unroll
    for (int g = 0; g < 4; ++g) {
        float4 s = (float4){0.f, 0.f, 0.f, 0.f};
#pragma unroll
        for (int ww = 0; ww < 4; ++ww) {
            const float4 a = *(const float4*)&xch[ww][bh][l * 16 + g * 4];
            s.x += a.x; s.y += a.y; s.z += a.z; s.w += a.w;
        }
        us[g*4] = s.x; us[g*4+1] = s.y; us[g*4+2] = s.z; us[g*4+3] = s.w;
    }

    const float rsqD = 0.17677669529663689f;  // 1/sqrt(32)
    f32x16 zc;
#pragma unroll
    for (int r = 0; r < 16; ++r) zc[r] = 0.f;

    for (int j = jbeg; j < jbeg + 32; j += 2) {
        bf16x8 a0 = *(const bf16x8*)(aBase + (size_t)j * 512);
        bf16x8 x0 = *(const bf16x8*)(bBase + (size_t)j * 16384);
        bf16x8 a1 = *(const bf16x8*)(aBase + (size_t)(j + 1) * 512);
        bf16x8 x1 = *(const bf16x8*)(bBase + (size_t)(j + 1) * 16384);
        f32x16 u0 = __builtin_amdgcn_mfma_f32_32x32x16_bf16(a0, x0, zc, 0, 0, 0);
        f32x16 u1 = __builtin_amdgcn_mfma_f32_32x32x16_bf16(a1, x1, zc, 0, 0, 0);
        float p0a = u0[0] * us[0], p0b = u0[1] * us[1];
        float p1a = u1[0] * us[0], p1b = u1[1] * us[1];
#pragma unroll
        for (int r = 2; r < 16; r += 2) {
            p0a = fmaf(u0[r],     us[r],     p0a);
            p0b = fmaf(u0[r + 1], us[r + 1], p0b);
            p1a = fmaf(u1[r],     us[r],     p1a);
            p1b = fmaf(u1[r + 1], us[r + 1], p1b);
        }
        float p0 = p0a + p0b;
        float p1 = p1a + p1b;
        p0 += __shfl_xor(p0, 32);
        p1 += __shfl_xor(p1, 32);
        const float p = (hi ? p1 : p0) * rsqD;
        uint_ pk = cvt_pk_bf16(p, p);
        LC[(size_t)(n * IN_N + j + hi) * 1024 + cb0 + bh * 32 + lo5] =
            (ushort_)(pk & 0xffffu);
    }
}

// ---------------------------------------------------------------------------
// kB: softmax over n per (b,j), 1 b per thread, fully coalesced; + bias.
// ---------------------------------------------------------------------------
__global__ __launch_bounds__(256)
void kB(const float* __restrict__ bias, ushort_* __restrict__ LC) {
    const int t = blockIdx.x * 256 + threadIdx.x;   // 131072 = 128j * 1024b
    const int j = t >> 10;                           // uniform per block
    const int b = t & 1023;
    float v[NCAP];
    float m = -1e30f;
#pragma unroll
    for (int n = 0; n < NCAP; ++n) {
        v[n] = bf16_to_f(LC[(size_t)(n * IN_N + j) * 1024 + b]);
        m = fmaxf(m, v[n]);
    }
    float s = 0.f;
#pragma unroll
    for (int n = 0; n < NCAP; ++n) { v[n] = __expf(v[n] - m); s += v[n]; }
    const float inv = 1.f / s;
#pragma unroll
    for (int n = 0; n < NCAP; ++n) {
        const float c = v[n] * inv + bias[n * IN_N + j];
        uint_ pk = cvt_pk_bf16(c, c);
        LC[(size_t)(n * IN_N + j) * 1024 + b] = (ushort_)(pk & 0xffffu);
    }
}

// ---------------------------------------------------------------------------
// kC: s[b,n,z] = sum_j c*u; 512 blocks x 512 threads, wave (jw,bh);
// jw=0 waves do epilogue (squash + store).
// ---------------------------------------------------------------------------
__global__ __launch_bounds__(512, 2)
void kC(const ushort_* __restrict__ XW, const ushort_* __restrict__ WT,
        const ushort_* __restrict__ LC, float* __restrict__ out) {
    const int raw = blockIdx.x;
    const int bid = ((raw & 7) << 6) | (raw >> 3);
    const int n   = bid >> 4;
    const int cb0 = (bid & 15) * 64;
    const int t   = threadIdx.x;
    const int w   = t >> 6;
    const int jw  = w >> 1;
    const int bh  = w & 1;
    const int l   = t & 63;
    const int lo5 = l & 31;
    const int hi  = l >> 5;

    __shared__ float xch[4][2][16 * 64];             // 32 KB

    const ushort_* aBase = WT + ((size_t)(n * IN_N) * 32 + lo5) * 16 + (size_t)hi * 8;
    const ushort_* bBase = XW + ((size_t)hi * 1024 + cb0 + bh * 32 + lo5) * 8;
    const ushort_* cBase = LC + (size_t)(n * IN_N) * 1024 + cb0 + bh * 32 + lo5;

    f32x16 s0, s1, zc;
#pragma unroll
    for (int r = 0; r < 16; ++r) { s0[r] = 0.f; s1[r] = 0.f; zc[r] = 0.f; }

    const int jbeg = jw * 32;
    for (int j = jbeg; j < jbeg + 32; j += 2) {
        bf16x8 a0 = *(const bf16x8*)(aBase + (size_t)j * 512);
        bf16x8 x0 = *(const bf16x8*)(bBase + (size_t)j * 16384);
        const float c0 = bf16_to_f(cBase[(size_t)j * 1024]);
        bf16x8 a1 = *(const bf16x8*)(aBase + (size_t)(j + 1) * 512);
        bf16x8 x1 = *(const bf16x8*)(bBase + (size_t)(j + 1) * 16384);
        const float c1 = bf16_to_f(cBase[(size_t)(j + 1) * 1024]);
        f32x16 u0 = __builtin_amdgcn_mfma_f32_32x32x16_bf16(a0, x0, zc, 0, 0, 0);
        f32x16 u1 = __builtin_amdgcn_mfma_f32_32x32x16_bf16(a1, x1, zc, 0, 0, 0);
#pragma unroll
        for (int r = 0; r < 16; ++r) {
            s0[r] = fmaf(c0, u0[r], s0[r]);
            s1[r] = fmaf(c1, u1[r], s1[r]);
        }
    }
#pragma unroll
    for (int r = 0; r < 16; ++r) s0[r] += s1[r];

    if (jw > 0) {
        float4* d = (float4*)&xch[jw][bh][l * 16];
#pragma unroll
        for (int g = 0; g < 4; ++g)
            d[g] = (float4){s0[g*4], s0[g*4+1], s0[g*4+2], s0[g*4+3]};
    }
    __syncthreads();

    if (jw == 0) {
#pragma unroll
        for (int g = 0; g < 4; ++g) {
#pragma unroll
            for (int ww = 1; ww < 4; ++ww) {
                const float4 a = *(const float4*)&xch[ww][bh][l * 16 + g * 4];
                s0[g*4]   += a.x; s0[g*4+1] += a.y;
                s0[g*4+2] += a.z; s0[g*4+3] += a.w;
            }
        }
        float q = 0.f;
#pragma unroll
        for (int r = 0; r < 16; ++r) q = fmaf(s0[r], s0[r], q);
        q += __shfl_xor(q, 32);                      // other half's 16 z's
        const float nn = sqrtf(q);
        const float f  = (1.f - 1.f / (__expf(nn) + 1e-20f)) / (nn + 1e-20f);
        // lane (lo5,hi), reg r -> z = (r&3) + 8*(r>>2) + 4*hi
        float* op = out + ((size_t)(cb0 + bh * 32 + lo5) * NCAP + n) * DCAP + hi * 4;
#pragma unroll
        for (int g = 0; g < 4; ++g) {
            float4 v4 = { s0[g*4] * f, s0[g*4+1] * f, s0[g*4+2] * f, s0[g*4+3] * f };
            *(float4*)(op + g * 8) = v4;
        }
    }
}

// ---------------------------------------------------------------------------
extern "C" void kernel_launch(void* const* d_in, const int* in_sizes, int n_in,
                              void* d_out, int out_size, void* d_ws, size_t ws_size,
                              hipStream_t stream) {
    const float* x    = (const float*)d_in[0];   // [1024,128,16]
    const float* W    = (const float*)d_in[1];   // [32,128,16,32]
    const float* bias = (const float*)d_in[2];   // [32,128,1]
    float* out = (float*)d_out;                  // [1024,32,32]

    char* ws = (char*)d_ws;
    ushort_* XW = (ushort_*)ws;                  // 4 MB bf16 x, relaid
    ushort_* WT = (ushort_*)(ws + (4u << 20));   // 4 MB bf16 W^T
    ushort_* LC = (ushort_*)(ws + (8u << 20));   // 8 MB bf16 logits/c

    prep<<<1024, 256, 0, stream>>>(x, W, XW, WT);
    kA<<<512, 512, 0, stream>>>(XW, WT, LC);
    kB<<<512, 256, 0, stream>>>(bias, LC);
    kC<<<512, 512, 0, stream>>>(XW, WT, LC, out);
}

// Round 6
// 57.195 us; speedup vs baseline: 1.2596x; 1.1386x over previous
//
#include <hip/hip_runtime.h>
#include <math.h>

#define B_TOT 1024
#define IN_N  128
#define IN_D  16
#define NCAP  32
#define DCAP  32

typedef __attribute__((ext_vector_type(8)))  short bf16x8;
typedef __attribute__((ext_vector_type(16))) float f32x16;
typedef unsigned int  uint_;
typedef unsigned short ushort_;

__device__ __forceinline__ uint_ cvt_pk_bf16(float lo, float hi) {
    uint_ r;
    asm("v_cvt_pk_bf16_f32 %0, %1, %2" : "=v"(r) : "v"(lo), "v"(hi));
    return r;
}
__device__ __forceinline__ float bf16_to_f(ushort_ h) {
    return __uint_as_float(((uint_)h) << 16);
}

// ---------------------------------------------------------------------------
// prep (fused): blocks [0,512): W[n][j][i][z] -> WT[((n*128+j)*32+z)*16+i] bf16
//               blocks [512,1024): x transpose -> XW[(j*2+ib)*1024+b][8] bf16
// prep_x uses an XOR-swizzled LDS tile (8B units, unit ^= row&15) so both the
// write (one 8B store/lane) and the read (two 8B loads/lane) are conflict-free
// (the old [64][72] ushort layout was an 8-way conflict on the 16B reads).
// ---------------------------------------------------------------------------
__global__ __launch_bounds__(256)
void prep(const float* __restrict__ x, const float* __restrict__ W,
          ushort_* __restrict__ XW, ushort_* __restrict__ WT) {
    const int blk = blockIdx.x;
    const int t   = threadIdx.x;

    if (blk < 512) {
        const int q  = blk * 256 + t;       // 131072 = 32n*128j*32z
        const int z  = q & 31;
        const int nj = q >> 5;
        const float* p = W + (size_t)nj * (IN_D * DCAP) + z;
        float f[16];
#pragma unroll
        for (int i = 0; i < 16; ++i) f[i] = p[i * 32];
        uint4 lo, hi;
        lo.x = cvt_pk_bf16(f[0],  f[1]);  lo.y = cvt_pk_bf16(f[2],  f[3]);
        lo.z = cvt_pk_bf16(f[4],  f[5]);  lo.w = cvt_pk_bf16(f[6],  f[7]);
        hi.x = cvt_pk_bf16(f[8],  f[9]);  hi.y = cvt_pk_bf16(f[10], f[11]);
        hi.z = cvt_pk_bf16(f[12], f[13]); hi.w = cvt_pk_bf16(f[14], f[15]);
        uint4* dst = (uint4*)(WT + (size_t)q * 16);
        dst[0] = lo; dst[1] = hi;
        return;
    }

    // prep_x: tile = 64 b x 64 cols (c = j*16+i); lds8[row][unit] of 8B units
    const int id = blk - 512;
    const int tb = id >> 5;
    const int tc = id & 31;
    const int b0 = tb * 64, c0 = tc * 64;

    __shared__ uint2 lds8[64][16];          // 8 KB, swizzled

    {
        const int c4 = t & 15;              // 8B unit index (4 bf16)
#pragma unroll
        for (int k = 0; k < 4; ++k) {
            const int r = (t >> 4) + 16 * k;
            const float4 f = *(const float4*)(x + (size_t)(b0 + r) * 2048 + c0 + c4 * 4);
            uint2 o;
            o.x = cvt_pk_bf16(f.x, f.y);
            o.y = cvt_pk_bf16(f.z, f.w);
            lds8[r][c4 ^ (r & 15)] = o;     // swizzled store, conflict-free
        }
    }
    __syncthreads();

    const int jb2l = t >> 5;                // 0..7 local output row
    const int jb20 = tc * 8;
#pragma unroll
    for (int h = 0; h < 2; ++h) {
        const int bl = (t & 31) + h * 32;
        const uint2 u0 = lds8[bl][(jb2l * 2)     ^ (bl & 15)];
        const uint2 u1 = lds8[bl][(jb2l * 2 + 1) ^ (bl & 15)];
        uint4 o; o.x = u0.x; o.y = u0.y; o.z = u1.x; o.w = u1.y;
        *(uint4*)(XW + ((size_t)(jb20 + jb2l) * 1024 + b0 + bl) * 8) = o;
    }
}

// ---------------------------------------------------------------------------
// kA: block = (n, 32-b tile), 4 waves x 32 j each (round-3 geometry).
// Phase 1: usum via 4 independent MFMA chains; cross-wave LDS combine.
// Phase 2: recompute u per j (REVERSED j order -> L1 reuse of phase-1 tail),
// dot with usum -> logits bf16.
// ---------------------------------------------------------------------------
__global__ __launch_bounds__(256, 5)
void kA(const ushort_* __restrict__ XW, const ushort_* __restrict__ WT,
        ushort_* __restrict__ LC) {
    const int bid = blockIdx.x;             // 1024 = 32n * 32 btiles
    const int n   = bid >> 5;
    const int cb0 = (bid & 31) * 32;
    const int t   = threadIdx.x;
    const int wv  = t >> 6;                 // 0..3
    const int l   = t & 63;
    const int lo5 = l & 31;
    const int hi  = l >> 5;

    __shared__ float xch[4][16 * 64];       // 16 KB

    const ushort_* aBase = WT + ((size_t)(n * IN_N) * 32 + lo5) * 16 + (size_t)hi * 8;
    const ushort_* bBase = XW + ((size_t)hi * 1024 + cb0 + lo5) * 8;

    const int jbeg = wv * 32;

    f32x16 us0, us1, us2, us3;
#pragma unroll
    for (int r = 0; r < 16; ++r) { us0[r] = 0.f; us1[r] = 0.f; us2[r] = 0.f; us3[r] = 0.f; }

    for (int j = jbeg; j < jbeg + 32; j += 4) {
        bf16x8 a0 = *(const bf16x8*)(aBase + (size_t)j * 512);
        bf16x8 x0 = *(const bf16x8*)(bBase + (size_t)j * 16384);
        bf16x8 a1 = *(const bf16x8*)(aBase + (size_t)(j + 1) * 512);
        bf16x8 x1 = *(const bf16x8*)(bBase + (size_t)(j + 1) * 16384);
        us0 = __builtin_amdgcn_mfma_f32_32x32x16_bf16(a0, x0, us0, 0, 0, 0);
        us1 = __builtin_amdgcn_mfma_f32_32x32x16_bf16(a1, x1, us1, 0, 0, 0);
        bf16x8 a2 = *(const bf16x8*)(aBase + (size_t)(j + 2) * 512);
        bf16x8 x2 = *(const bf16x8*)(bBase + (size_t)(j + 2) * 16384);
        bf16x8 a3 = *(const bf16x8*)(aBase + (size_t)(j + 3) * 512);
        bf16x8 x3 = *(const bf16x8*)(bBase + (size_t)(j + 3) * 16384);
        us2 = __builtin_amdgcn_mfma_f32_32x32x16_bf16(a2, x2, us2, 0, 0, 0);
        us3 = __builtin_amdgcn_mfma_f32_32x32x16_bf16(a3, x3, us3, 0, 0, 0);
    }
#pragma unroll
    for (int r = 0; r < 16; ++r)
        us0[r] = (us0[r] + us1[r]) + (us2[r] + us3[r]);

#pragma unroll
    for (int r = 0; r < 16; ++r) xch[wv][r * 64 + l] = us0[r];
    __syncthreads();

    f32x16 us;
#pragma unroll
    for (int r = 0; r < 16; ++r)
        us[r] = (xch[0][r * 64 + l] + xch[1][r * 64 + l]) +
                (xch[2][r * 64 + l] + xch[3][r * 64 + l]);

    const float rsqD = 0.17677669529663689f;  // 1/sqrt(32)
    f32x16 zc;
#pragma unroll
    for (int r = 0; r < 16; ++r) zc[r] = 0.f;

#pragma unroll 2
    for (int j = jbeg + 31; j >= jbeg; --j) {   // reversed: phase-1 tail is L1-hot
        bf16x8 af = *(const bf16x8*)(aBase + (size_t)j * 512);
        bf16x8 xf = *(const bf16x8*)(bBase + (size_t)j * 16384);
        f32x16 u = __builtin_amdgcn_mfma_f32_32x32x16_bf16(af, xf, zc, 0, 0, 0);
        float p0 = u[0] * us[0], p1 = u[1] * us[1];
        float p2 = u[2] * us[2], p3 = u[3] * us[3];
#pragma unroll
        for (int r = 4; r < 16; r += 4) {
            p0 = fmaf(u[r],     us[r],     p0);
            p1 = fmaf(u[r + 1], us[r + 1], p1);
            p2 = fmaf(u[r + 2], us[r + 2], p2);
            p3 = fmaf(u[r + 3], us[r + 3], p3);
        }
        float p = (p0 + p1) + (p2 + p3);
        p += __shfl_xor(p, 32);
        p *= rsqD;
        if (l < 32) {
            uint_ pk = cvt_pk_bf16(p, p);
            LC[(size_t)(n * IN_N + j) * 1024 + cb0 + lo5] = (ushort_)(pk & 0xffffu);
        }
    }
}

// ---------------------------------------------------------------------------
// kB: softmax over n per (b,j), 1 b per thread, fully coalesced; + bias.
// ---------------------------------------------------------------------------
__global__ __launch_bounds__(256)
void kB(const float* __restrict__ bias, ushort_* __restrict__ LC) {
    const int t = blockIdx.x * 256 + threadIdx.x;   // 131072 = 128j * 1024b
    const int j = t >> 10;                           // uniform per block
    const int b = t & 1023;
    float v[NCAP];
    float m = -1e30f;
#pragma unroll
    for (int n = 0; n < NCAP; ++n) {
        v[n] = bf16_to_f(LC[(size_t)(n * IN_N + j) * 1024 + b]);
        m = fmaxf(m, v[n]);
    }
    float s = 0.f;
#pragma unroll
    for (int n = 0; n < NCAP; ++n) { v[n] = __expf(v[n] - m); s += v[n]; }
    const float inv = 1.f / s;
#pragma unroll
    for (int n = 0; n < NCAP; ++n) {
        const float c = v[n] * inv + bias[n * IN_N + j];
        uint_ pk = cvt_pk_bf16(c, c);
        LC[(size_t)(n * IN_N + j) * 1024 + b] = (ushort_)(pk & 0xffffu);
    }
}

// ---------------------------------------------------------------------------
// kC: s[b,n,z] = sum_j c*u; round-3 geometry, single s-chain (inter-j FMA
// dependence distance is long enough); wave-0 epilogue.
// ---------------------------------------------------------------------------
__global__ __launch_bounds__(256, 5)
void kC(const ushort_* __restrict__ XW, const ushort_* __restrict__ WT,
        const ushort_* __restrict__ LC, float* __restrict__ out) {
    const int bid = blockIdx.x;
    const int n   = bid >> 5;
    const int cb0 = (bid & 31) * 32;
    const int t   = threadIdx.x;
    const int wv  = t >> 6;
    const int l   = t & 63;
    const int lo5 = l & 31;
    const int hi  = l >> 5;

    __shared__ float xch[3][16 * 64];       // 12 KB

    const ushort_* aBase = WT + ((size_t)(n * IN_N) * 32 + lo5) * 16 + (size_t)hi * 8;
    const ushort_* bBase = XW + ((size_t)hi * 1024 + cb0 + lo5) * 8;
    const ushort_* cBase = LC + (size_t)(n * IN_N) * 1024 + cb0 + lo5;

    f32x16 s0, zc;
#pragma unroll
    for (int r = 0; r < 16; ++r) { s0[r] = 0.f; zc[r] = 0.f; }

    const int jbeg = wv * 32;
#pragma unroll 2
    for (int j = jbeg; j < jbeg + 32; ++j) {
        bf16x8 af = *(const bf16x8*)(aBase + (size_t)j * 512);
        bf16x8 xf = *(const bf16x8*)(bBase + (size_t)j * 16384);
        const float c = bf16_to_f(cBase[(size_t)j * 1024]);
        f32x16 u = __builtin_amdgcn_mfma_f32_32x32x16_bf16(af, xf, zc, 0, 0, 0);
#pragma unroll
        for (int r = 0; r < 16; ++r) s0[r] = fmaf(c, u[r], s0[r]);
    }

    if (wv > 0) {
#pragma unroll
        for (int r = 0; r < 16; ++r) xch[wv - 1][r * 64 + l] = s0[r];
    }
    __syncthreads();

    if (wv == 0) {
#pragma unroll
        for (int r = 0; r < 16; ++r)
            s0[r] += (xch[0][r * 64 + l] + xch[1][r * 64 + l]) + xch[2][r * 64 + l];
        float q0 = s0[0] * s0[0], q1 = s0[1] * s0[1];
        float q2 = s0[2] * s0[2], q3 = s0[3] * s0[3];
#pragma unroll
        for (int r = 4; r < 16; r += 4) {
            q0 = fmaf(s0[r],     s0[r],     q0);
            q1 = fmaf(s0[r + 1], s0[r + 1], q1);
            q2 = fmaf(s0[r + 2], s0[r + 2], q2);
            q3 = fmaf(s0[r + 3], s0[r + 3], q3);
        }
        float q = (q0 + q1) + (q2 + q3);
        q += __shfl_xor(q, 32);             // other half's 16 z's
        const float nn = sqrtf(q);
        const float f  = (1.f - 1.f / (__expf(nn) + 1e-20f)) / (nn + 1e-20f);
        // lane (lo5,hi), reg r -> z = (r&3) + 8*(r>>2) + 4*hi
        float* op = out + ((size_t)(cb0 + lo5) * NCAP + n) * DCAP + hi * 4;
#pragma unroll
        for (int g = 0; g < 4; ++g) {
            float4 v4 = { s0[g*4] * f, s0[g*4+1] * f, s0[g*4+2] * f, s0[g*4+3] * f };
            *(float4*)(op + g * 8) = v4;
        }
    }
}

// ---------------------------------------------------------------------------
extern "C" void kernel_launch(void* const* d_in, const int* in_sizes, int n_in,
                              void* d_out, int out_size, void* d_ws, size_t ws_size,
                              hipStream_t stream) {
    const float* x    = (const float*)d_in[0];   // [1024,128,16]
    const float* W    = (const float*)d_in[1];   // [32,128,16,32]
    const float* bias = (const float*)d_in[2];   // [32,128,1]
    float* out = (float*)d_out;                  // [1024,32,32]

    char* ws = (char*)d_ws;
    ushort_* XW = (ushort_*)ws;                  // 4 MB bf16 x, relaid
    ushort_* WT = (ushort_*)(ws + (4u << 20));   // 4 MB bf16 W^T
    ushort_* LC = (ushort_*)(ws + (8u << 20));   // 8 MB bf16 logits/c

    prep<<<1024, 256, 0, stream>>>(x, W, XW, WT);
    kA<<<1024, 256, 0, stream>>>(XW, WT, LC);
    kB<<<512, 256, 0, stream>>>(bias, LC);
    kC<<<1024, 256, 0, stream>>>(XW, WT, LC, out);
}

// Round 7
// 54.022 us; speedup vs baseline: 1.3336x; 1.0587x over previous
//
#include <hip/hip_runtime.h>
#include <math.h>

#define B_TOT 1024
#define IN_N  128
#define IN_D  16
#define NCAP  32
#define DCAP  32

typedef __attribute__((ext_vector_type(8)))  short bf16x8;
typedef __attribute__((ext_vector_type(16))) float f32x16;
typedef unsigned int  uint_;
typedef unsigned short ushort_;

__device__ __forceinline__ uint_ cvt_pk_bf16(float lo, float hi) {
    uint_ r;
    asm("v_cvt_pk_bf16_f32 %0, %1, %2" : "=v"(r) : "v"(lo), "v"(hi));
    return r;
}
__device__ __forceinline__ float bf16_to_f(ushort_ h) {
    return __uint_as_float(((uint_)h) << 16);
}

// ---------------------------------------------------------------------------
// prep (fused): blocks [0,512): W[n][j][i][z] -> WT[((n*128+j)*32+z)*16+i] bf16
//               blocks [512,1024): x transpose -> XW[(j*2+ib)*1024+b][8] bf16
// prep_x uses an XOR-swizzled LDS tile (8B units, unit ^= row&15): both the
// write (one 8B store/lane) and read (two 8B loads/lane) are conflict-free.
// ---------------------------------------------------------------------------
__global__ __launch_bounds__(256)
void prep(const float* __restrict__ x, const float* __restrict__ W,
          ushort_* __restrict__ XW, ushort_* __restrict__ WT) {
    const int blk = blockIdx.x;
    const int t   = threadIdx.x;

    if (blk < 512) {
        const int q  = blk * 256 + t;       // 131072 = 32n*128j*32z
        const int z  = q & 31;
        const int nj = q >> 5;
        const float* p = W + (size_t)nj * (IN_D * DCAP) + z;
        float f[16];
#pragma unroll
        for (int i = 0; i < 16; ++i) f[i] = p[i * 32];
        uint4 lo, hi;
        lo.x = cvt_pk_bf16(f[0],  f[1]);  lo.y = cvt_pk_bf16(f[2],  f[3]);
        lo.z = cvt_pk_bf16(f[4],  f[5]);  lo.w = cvt_pk_bf16(f[6],  f[7]);
        hi.x = cvt_pk_bf16(f[8],  f[9]);  hi.y = cvt_pk_bf16(f[10], f[11]);
        hi.z = cvt_pk_bf16(f[12], f[13]); hi.w = cvt_pk_bf16(f[14], f[15]);
        uint4* dst = (uint4*)(WT + (size_t)q * 16);
        dst[0] = lo; dst[1] = hi;
        return;
    }

    // prep_x: tile = 64 b x 64 cols (c = j*16+i); lds8[row][unit] of 8B units
    const int id = blk - 512;
    const int tb = id >> 5;
    const int tc = id & 31;
    const int b0 = tb * 64, c0 = tc * 64;

    __shared__ uint2 lds8[64][16];          // 8 KB, swizzled

    {
        const int c4 = t & 15;              // 8B unit index (4 bf16)
#pragma unroll
        for (int k = 0; k < 4; ++k) {
            const int r = (t >> 4) + 16 * k;
            const float4 f = *(const float4*)(x + (size_t)(b0 + r) * 2048 + c0 + c4 * 4);
            uint2 o;
            o.x = cvt_pk_bf16(f.x, f.y);
            o.y = cvt_pk_bf16(f.z, f.w);
            lds8[r][c4 ^ (r & 15)] = o;     // swizzled store, conflict-free
        }
    }
    __syncthreads();

    const int jb2l = t >> 5;                // 0..7 local output row
    const int jb20 = tc * 8;
#pragma unroll
    for (int h = 0; h < 2; ++h) {
        const int bl = (t & 31) + h * 32;
        const uint2 u0 = lds8[bl][(jb2l * 2)     ^ (bl & 15)];
        const uint2 u1 = lds8[bl][(jb2l * 2 + 1) ^ (bl & 15)];
        uint4 o; o.x = u0.x; o.y = u0.y; o.z = u1.x; o.w = u1.y;
        *(uint4*)(XW + ((size_t)(jb20 + jb2l) * 1024 + b0 + bl) * 8) = o;
    }
}

// ---------------------------------------------------------------------------
// kA: block = (n, 32-b tile), 4 waves x 32 j each.
// Phase 1: usum via 4 independent MFMA chains; cross-wave LDS combine.
// Phase 2: batched-4 j-groups (8 loads in flight), reversed batch order for
// L1 reuse of phase-1 tail; paired full-wave logit stores.
// ---------------------------------------------------------------------------
__global__ __launch_bounds__(256, 4)
void kA(const ushort_* __restrict__ XW, const ushort_* __restrict__ WT,
        ushort_* __restrict__ LC) {
    const int bid = blockIdx.x;             // 1024 = 32n * 32 btiles
    const int n   = bid >> 5;
    const int cb0 = (bid & 31) * 32;
    const int t   = threadIdx.x;
    const int wv  = t >> 6;                 // 0..3
    const int l   = t & 63;
    const int lo5 = l & 31;
    const int hi  = l >> 5;

    __shared__ float xch[4][16 * 64];       // 16 KB

    const ushort_* aBase = WT + ((size_t)(n * IN_N) * 32 + lo5) * 16 + (size_t)hi * 8;
    const ushort_* bBase = XW + ((size_t)hi * 1024 + cb0 + lo5) * 8;

    const int jbeg = wv * 32;

    f32x16 us0, us1, us2, us3;
#pragma unroll
    for (int r = 0; r < 16; ++r) { us0[r] = 0.f; us1[r] = 0.f; us2[r] = 0.f; us3[r] = 0.f; }

    for (int j = jbeg; j < jbeg + 32; j += 4) {
        bf16x8 a0 = *(const bf16x8*)(aBase + (size_t)j * 512);
        bf16x8 x0 = *(const bf16x8*)(bBase + (size_t)j * 16384);
        bf16x8 a1 = *(const bf16x8*)(aBase + (size_t)(j + 1) * 512);
        bf16x8 x1 = *(const bf16x8*)(bBase + (size_t)(j + 1) * 16384);
        us0 = __builtin_amdgcn_mfma_f32_32x32x16_bf16(a0, x0, us0, 0, 0, 0);
        us1 = __builtin_amdgcn_mfma_f32_32x32x16_bf16(a1, x1, us1, 0, 0, 0);
        bf16x8 a2 = *(const bf16x8*)(aBase + (size_t)(j + 2) * 512);
        bf16x8 x2 = *(const bf16x8*)(bBase + (size_t)(j + 2) * 16384);
        bf16x8 a3 = *(const bf16x8*)(aBase + (size_t)(j + 3) * 512);
        bf16x8 x3 = *(const bf16x8*)(bBase + (size_t)(j + 3) * 16384);
        us2 = __builtin_amdgcn_mfma_f32_32x32x16_bf16(a2, x2, us2, 0, 0, 0);
        us3 = __builtin_amdgcn_mfma_f32_32x32x16_bf16(a3, x3, us3, 0, 0, 0);
    }
#pragma unroll
    for (int r = 0; r < 16; ++r)
        us0[r] = (us0[r] + us1[r]) + (us2[r] + us3[r]);

#pragma unroll
    for (int r = 0; r < 16; ++r) xch[wv][r * 64 + l] = us0[r];
    __syncthreads();

    f32x16 us;
#pragma unroll
    for (int r = 0; r < 16; ++r)
        us[r] = (xch[0][r * 64 + l] + xch[1][r * 64 + l]) +
                (xch[2][r * 64 + l] + xch[3][r * 64 + l]);

    const float rsqD = 0.17677669529663689f;  // 1/sqrt(32)
    f32x16 zc;
#pragma unroll
    for (int r = 0; r < 16; ++r) zc[r] = 0.f;

    for (int jb = jbeg + 28; jb >= jbeg; jb -= 4) {  // reversed batches: L1-hot tail
        bf16x8 a0 = *(const bf16x8*)(aBase + (size_t)jb * 512);
        bf16x8 x0 = *(const bf16x8*)(bBase + (size_t)jb * 16384);
        bf16x8 a1 = *(const bf16x8*)(aBase + (size_t)(jb + 1) * 512);
        bf16x8 x1 = *(const bf16x8*)(bBase + (size_t)(jb + 1) * 16384);
        bf16x8 a2 = *(const bf16x8*)(aBase + (size_t)(jb + 2) * 512);
        bf16x8 x2 = *(const bf16x8*)(bBase + (size_t)(jb + 2) * 16384);
        bf16x8 a3 = *(const bf16x8*)(aBase + (size_t)(jb + 3) * 512);
        bf16x8 x3 = *(const bf16x8*)(bBase + (size_t)(jb + 3) * 16384);
        f32x16 u0 = __builtin_amdgcn_mfma_f32_32x32x16_bf16(a0, x0, zc, 0, 0, 0);
        f32x16 u1 = __builtin_amdgcn_mfma_f32_32x32x16_bf16(a1, x1, zc, 0, 0, 0);
        f32x16 u2 = __builtin_amdgcn_mfma_f32_32x32x16_bf16(a2, x2, zc, 0, 0, 0);
        f32x16 u3 = __builtin_amdgcn_mfma_f32_32x32x16_bf16(a3, x3, zc, 0, 0, 0);

        float p0a = u0[0] * us[0], p0b = u0[1] * us[1];
        float p1a = u1[0] * us[0], p1b = u1[1] * us[1];
        float p2a = u2[0] * us[0], p2b = u2[1] * us[1];
        float p3a = u3[0] * us[0], p3b = u3[1] * us[1];
#pragma unroll
        for (int r = 2; r < 16; r += 2) {
            p0a = fmaf(u0[r], us[r], p0a); p0b = fmaf(u0[r + 1], us[r + 1], p0b);
            p1a = fmaf(u1[r], us[r], p1a); p1b = fmaf(u1[r + 1], us[r + 1], p1b);
            p2a = fmaf(u2[r], us[r], p2a); p2b = fmaf(u2[r + 1], us[r + 1], p2b);
            p3a = fmaf(u3[r], us[r], p3a); p3b = fmaf(u3[r + 1], us[r + 1], p3b);
        }
        float p0 = p0a + p0b, p1 = p1a + p1b, p2 = p2a + p2b, p3 = p3a + p3b;
        p0 += __shfl_xor(p0, 32);
        p1 += __shfl_xor(p1, 32);
        p2 += __shfl_xor(p2, 32);
        p3 += __shfl_xor(p3, 32);
        // paired stores: lanes 0-31 store row jb+k, lanes 32-63 row jb+k+1
        const float q01 = (hi ? p1 : p0) * rsqD;
        const float q23 = (hi ? p3 : p2) * rsqD;
        uint_ k01 = cvt_pk_bf16(q01, q01);
        uint_ k23 = cvt_pk_bf16(q23, q23);
        LC[(size_t)(n * IN_N + jb + hi) * 1024 + cb0 + lo5]     = (ushort_)(k01 & 0xffffu);
        LC[(size_t)(n * IN_N + jb + 2 + hi) * 1024 + cb0 + lo5] = (ushort_)(k23 & 0xffffu);
    }
}

// ---------------------------------------------------------------------------
// kB: softmax over n per (b,j), 1 b per thread, fully coalesced; + bias.
// ---------------------------------------------------------------------------
__global__ __launch_bounds__(256)
void kB(const float* __restrict__ bias, ushort_* __restrict__ LC) {
    const int t = blockIdx.x * 256 + threadIdx.x;   // 131072 = 128j * 1024b
    const int j = t >> 10;                           // uniform per block
    const int b = t & 1023;
    float v[NCAP];
    float m = -1e30f;
#pragma unroll
    for (int n = 0; n < NCAP; ++n) {
        v[n] = bf16_to_f(LC[(size_t)(n * IN_N + j) * 1024 + b]);
        m = fmaxf(m, v[n]);
    }
    float s = 0.f;
#pragma unroll
    for (int n = 0; n < NCAP; ++n) { v[n] = __expf(v[n] - m); s += v[n]; }
    const float inv = 1.f / s;
#pragma unroll
    for (int n = 0; n < NCAP; ++n) {
        const float c = v[n] * inv + bias[n * IN_N + j];
        uint_ pk = cvt_pk_bf16(c, c);
        LC[(size_t)(n * IN_N + j) * 1024 + b] = (ushort_)(pk & 0xffffu);
    }
}

// ---------------------------------------------------------------------------
// kC: s[b,n,z] = sum_j c*u; batched-4 j-groups (8 frag + 4 c loads in
// flight), single s-chain; wave-0 epilogue (squash + store).
// ---------------------------------------------------------------------------
__global__ __launch_bounds__(256, 4)
void kC(const ushort_* __restrict__ XW, const ushort_* __restrict__ WT,
        const ushort_* __restrict__ LC, float* __restrict__ out) {
    const int bid = blockIdx.x;
    const int n   = bid >> 5;
    const int cb0 = (bid & 31) * 32;
    const int t   = threadIdx.x;
    const int wv  = t >> 6;
    const int l   = t & 63;
    const int lo5 = l & 31;
    const int hi  = l >> 5;

    __shared__ float xch[3][16 * 64];       // 12 KB

    const ushort_* aBase = WT + ((size_t)(n * IN_N) * 32 + lo5) * 16 + (size_t)hi * 8;
    const ushort_* bBase = XW + ((size_t)hi * 1024 + cb0 + lo5) * 8;
    const ushort_* cBase = LC + (size_t)(n * IN_N) * 1024 + cb0 + lo5;

    f32x16 s0, zc;
#pragma unroll
    for (int r = 0; r < 16; ++r) { s0[r] = 0.f; zc[r] = 0.f; }

    const int jbeg = wv * 32;
    for (int jb = jbeg; jb < jbeg + 32; jb += 4) {
        bf16x8 a0 = *(const bf16x8*)(aBase + (size_t)jb * 512);
        bf16x8 x0 = *(const bf16x8*)(bBase + (size_t)jb * 16384);
        bf16x8 a1 = *(const bf16x8*)(aBase + (size_t)(jb + 1) * 512);
        bf16x8 x1 = *(const bf16x8*)(bBase + (size_t)(jb + 1) * 16384);
        bf16x8 a2 = *(const bf16x8*)(aBase + (size_t)(jb + 2) * 512);
        bf16x8 x2 = *(const bf16x8*)(bBase + (size_t)(jb + 2) * 16384);
        bf16x8 a3 = *(const bf16x8*)(aBase + (size_t)(jb + 3) * 512);
        bf16x8 x3 = *(const bf16x8*)(bBase + (size_t)(jb + 3) * 16384);
        const float c0 = bf16_to_f(cBase[(size_t)jb * 1024]);
        const float c1 = bf16_to_f(cBase[(size_t)(jb + 1) * 1024]);
        const float c2 = bf16_to_f(cBase[(size_t)(jb + 2) * 1024]);
        const float c3 = bf16_to_f(cBase[(size_t)(jb + 3) * 1024]);
        f32x16 u0 = __builtin_amdgcn_mfma_f32_32x32x16_bf16(a0, x0, zc, 0, 0, 0);
        f32x16 u1 = __builtin_amdgcn_mfma_f32_32x32x16_bf16(a1, x1, zc, 0, 0, 0);
        f32x16 u2 = __builtin_amdgcn_mfma_f32_32x32x16_bf16(a2, x2, zc, 0, 0, 0);
        f32x16 u3 = __builtin_amdgcn_mfma_f32_32x32x16_bf16(a3, x3, zc, 0, 0, 0);
#pragma unroll
        for (int r = 0; r < 16; ++r) {
            float acc = fmaf(c0, u0[r], s0[r]);
            acc = fmaf(c1, u1[r], acc);
            acc = fmaf(c2, u2[r], acc);
            s0[r] = fmaf(c3, u3[r], acc);
        }
    }

    if (wv > 0) {
#pragma unroll
        for (int r = 0; r < 16; ++r) xch[wv - 1][r * 64 + l] = s0[r];
    }
    __syncthreads();

    if (wv == 0) {
#pragma unroll
        for (int r = 0; r < 16; ++r)
            s0[r] += (xch[0][r * 64 + l] + xch[1][r * 64 + l]) + xch[2][r * 64 + l];
        float q0 = s0[0] * s0[0], q1 = s0[1] * s0[1];
        float q2 = s0[2] * s0[2], q3 = s0[3] * s0[3];
#pragma unroll
        for (int r = 4; r < 16; r += 4) {
            q0 = fmaf(s0[r],     s0[r],     q0);
            q1 = fmaf(s0[r + 1], s0[r + 1], q1);
            q2 = fmaf(s0[r + 2], s0[r + 2], q2);
            q3 = fmaf(s0[r + 3], s0[r + 3], q3);
        }
        float q = (q0 + q1) + (q2 + q3);
        q += __shfl_xor(q, 32);             // other half's 16 z's
        const float nn = sqrtf(q);
        const float f  = (1.f - 1.f / (__expf(nn) + 1e-20f)) / (nn + 1e-20f);
        // lane (lo5,hi), reg r -> z = (r&3) + 8*(r>>2) + 4*hi
        float* op = out + ((size_t)(cb0 + lo5) * NCAP + n) * DCAP + hi * 4;
#pragma unroll
        for (int g = 0; g < 4; ++g) {
            float4 v4 = { s0[g*4] * f, s0[g*4+1] * f, s0[g*4+2] * f, s0[g*4+3] * f };
            *(float4*)(op + g * 8) = v4;
        }
    }
}

// ---------------------------------------------------------------------------
extern "C" void kernel_launch(void* const* d_in, const int* in_sizes, int n_in,
                              void* d_out, int out_size, void* d_ws, size_t ws_size,
                              hipStream_t stream) {
    const float* x    = (const float*)d_in[0];   // [1024,128,16]
    const float* W    = (const float*)d_in[1];   // [32,128,16,32]
    const float* bias = (const float*)d_in[2];   // [32,128,1]
    float* out = (float*)d_out;                  // [1024,32,32]

    char* ws = (char*)d_ws;
    ushort_* XW = (ushort_*)ws;                  // 4 MB bf16 x, relaid
    ushort_* WT = (ushort_*)(ws + (4u << 20));   // 4 MB bf16 W^T
    ushort_* LC = (ushort_*)(ws + (8u << 20));   // 8 MB bf16 logits/c

    prep<<<1024, 256, 0, stream>>>(x, W, XW, WT);
    kA<<<1024, 256, 0, stream>>>(XW, WT, LC);
    kB<<<512, 256, 0, stream>>>(bias, LC);
    kC<<<1024, 256, 0, stream>>>(XW, WT, LC, out);
}